// Round 8
// baseline (4798.881 us; speedup 1.0000x reference)
//
#include <hip/hip_runtime.h>
#include <math.h>
#include <utility>

#define DI __device__ __forceinline__

namespace {

typedef unsigned short u16;
typedef unsigned int u32;
using f16x8 = __attribute__((ext_vector_type(8))) _Float16;
using f32x4 = __attribute__((ext_vector_type(4))) float;

constexpr int BB  = 8;
constexpr int CIN = 3;
constexpr int HIN = 128, WIN = 256;
constexpr int EE  = 256;
constexpr int NSP = BB * 32 * 64;   // 16384
constexpr double PI_D = 3.14159265358979323846;
constexpr int ME_ENC = 5120, ME_INT = 2048, ME_DEC = 4608;
constexpr int HW_E = 34;            // encoder hi-window rows per ho

DI u16 f16rne(float x) { _Float16 h = (_Float16)x; return __builtin_bit_cast(unsigned short, h); }
DI float f16tof(u16 u) { return (float)__builtin_bit_cast(_Float16, u); }
DI u32 packhl(float v) {
  u16 h = f16rne(v);
  u16 l = f16rne(v - f16tof(h));
  return (u32)h | ((u32)l << 16);
}

// ---------------- psi evaluation (double, matches numpy f64 build) ----------------
DI bool psi_point(int nlat_in, int nlon_in, int nlat_out, double cutoff,
                  int ho, int hi, int d, bool wantv, float* out9)
{
  double ti = PI_D * (hi + 0.5) / nlat_in;
  double to = PI_D * (ho + 0.5) / nlat_out;
  double ph = 2.0 * PI_D * d / nlon_in;
  double cto = cos(to), sto = sin(to);
  double cti = cos(ti), sti = sin(ti);
  double cph = cos(ph), sph = sin(ph);
  double ca = cto * cti + sto * sti * cph;
  ca = fmin(1.0, fmax(-1.0, ca));
  double r = acos(ca);
  if (r > cutoff) return false;
  if (wantv) {
    double dr   = cutoff * 0.5;
    double dphi = PI_D * 0.5;
    double quad = sti * (PI_D / nlat_in) * (2.0 * PI_D / nlon_in);
    out9[0] = (float)(fmin(1.0, fmax(0.0, 1.0 - r / dr)) * quad);
    double alpha = atan2(sti * sph, cti * sto - sti * cto * cph);
#pragma unroll
    for (int j = 1; j <= 2; ++j) {
      double tr = fmin(1.0, fmax(0.0, 1.0 - fabs(r - j * dr) / dr));
#pragma unroll
      for (int k2 = 0; k2 < 4; ++k2) {
        double xx = alpha - k2 * dphi + PI_D;
        double yy = xx - 2.0 * PI_D * floor(xx / (2.0 * PI_D));
        double dd = fabs(yy - PI_D);
        out9[1 + (j - 1) * 4 + k2] = (float)(tr * fmin(1.0, fmax(0.0, 1.0 - dd / dphi)) * quad);
      }
    }
  }
  return true;
}

__global__ void k_psi_count(int nlat_in, int nlon_in, int nlat_out, double cutoff, int* cnt)
{
  int hi = blockIdx.x, ho = blockIdx.y, d = threadIdx.x;
  float dummy[9];
  bool in = psi_point(nlat_in, nlon_in, nlat_out, cutoff, ho, hi, d, false, dummy);
  unsigned long long mask = __ballot(in);
  if ((threadIdx.x & 63) == 0) {
    int tot = __popcll(mask);
    if (tot) atomicAdd(cnt + ho * nlat_in + hi, tot);
  }
}

__global__ void k_psi_scan(int nlat_in, int maxe, int* cnt, int* offs)
{
  int ho = blockIdx.x;
  int* c = cnt + ho * nlat_in;
  int* o = offs + ho * (nlat_in + 1);
  int run = 0;
  for (int hi = 0; hi < nlat_in; ++hi) {
    o[hi] = run < maxe ? run : maxe;
    run += c[hi];
    c[hi] = 0;
  }
  o[nlat_in] = run < maxe ? run : maxe;
}

__global__ void k_psi_fill(int nlat_in, int nlon_in, int nlat_out, double cutoff,
                           int maxe, int* cnt, const int* __restrict__ offs, float* __restrict__ tab)
{
  int hi = blockIdx.x, ho = blockIdx.y, d = threadIdx.x;
  float p9[9];
  bool in = psi_point(nlat_in, nlon_in, nlat_out, cutoff, ho, hi, d, true, p9);
  unsigned long long mask = __ballot(in);
  int lane = threadIdx.x & 63;
  int tot = __popcll(mask);
  int wbase = 0;
  if (lane == 0 && tot) wbase = atomicAdd(cnt + ho * nlat_in + hi, tot);
  wbase = __shfl(wbase, 0, 64);
  if (in) {
    int rank = __popcll(mask & ((1ull << lane) - 1ull));
    int idx = offs[ho * (nlat_in + 1) + hi] + wbase + rank;
    if (idx < maxe) {
      float* te = tab + ((size_t)ho * maxe + idx) * 12;
      te[0] = __int_as_float((hi << 16) | d);
#pragma unroll
      for (int k = 0; k < 9; ++k) te[1 + k] = p9[k];
      te[10] = 0.f; te[11] = 0.f;
    }
  }
}

// ---------------- Legendre PW/PT + twiddles ----------------
__global__ void k_legendre(float* __restrict__ PW, float* __restrict__ PT)
{
  int h = threadIdx.x;
  if (h >= 32) return;
  double th = PI_D * (h + 0.5) / 32.0;
  double ct = cos(th), st = sin(th);
  double quad = st * (PI_D / 32.0);
  double diag = 0.70710678118654752440;
  for (int m = 0; m < 32; ++m) {
    if (m > 0) diag = sqrt((2.0 * m + 1.0) / (2.0 * m)) * st * diag;
    double plm2 = diag;
    PT[((size_t)m * 32 + m) * 32 + h] = (float)plm2;
    PW[((size_t)m * 32 + m) * 32 + h] = (float)(plm2 * quad);
    if (m + 1 < 32) {
      double plm1 = sqrt(2.0 * m + 3.0) * ct * diag;
      PT[((size_t)(m + 1) * 32 + m) * 32 + h] = (float)plm1;
      PW[((size_t)(m + 1) * 32 + m) * 32 + h] = (float)(plm1 * quad);
      for (int l = m + 2; l < 32; ++l) {
        double a  = sqrt((4.0 * l * l - 1.0) / ((double)l * l - (double)m * m));
        double bb = a * sqrt((((double)(l - 1) * (l - 1)) - (double)m * m) /
                             (4.0 * (double)(l - 1) * (l - 1) - 1.0));
        double p = a * ct * plm1 - bb * plm2;
        PT[((size_t)l * 32 + m) * 32 + h] = (float)p;
        PW[((size_t)l * 32 + m) * 32 + h] = (float)(p * quad);
        plm2 = plm1; plm1 = p;
      }
    }
    for (int l = 0; l < m; ++l) {
      PT[((size_t)l * 32 + m) * 32 + h] = 0.f;
      PW[((size_t)l * 32 + m) * 32 + h] = 0.f;
    }
  }
}

__global__ void k_tw2(float* tc256, float* ts256, float* tc64, float* ts64)
{
  int t = threadIdx.x;
  double th = 2.0 * PI_D * t / 256.0;
  tc256[t] = (float)cos(th);
  ts256[t] = (float)sin(th);
  if (t < 64) {
    double th2 = 2.0 * PI_D * t / 64.0;
    tc64[t] = (float)cos(th2);
    ts64[t] = (float)sin(th2);
  }
}

// twiddle MATRICES for DFT-as-GEMM, pre-split packed u32 (f16hi | f16lo<<16)
__global__ void k_twmat(u32* __restrict__ tw256, u32* __restrict__ itw256,
                        u32* __restrict__ tw64, u32* __restrict__ itw64,
                        u32* __restrict__ iffold)
{
  int t = blockIdx.x * 256 + threadIdx.x;
  if (t < 256 * 129) {                       // tw256 [w 256][258]
    int w = t / 129, m = t % 129;
    double th = 2.0 * PI_D * ((m * w) & 255) / 256.0;
    tw256[w * 258 + 2 * m]     = packhl((float)cos(th));
    tw256[w * 258 + 2 * m + 1] = packhl((float)(-sin(th)));
  }
  if (t < 129 * 256) {                       // itw256 [258][256]
    int m = t >> 8, w = t & 255;
    double th = 2.0 * PI_D * ((m * w) & 255) / 256.0;
    float cr, ci;
    if (m == 0)        { cr = 1.f / 256.f; ci = 0.f; }
    else if (m == 128) { cr = ((w & 1) ? -1.f : 1.f) / 256.f; ci = 0.f; }
    else { cr = (float)(2.0 * cos(th) / 256.0); ci = (float)(-2.0 * sin(th) / 256.0); }
    itw256[(2 * m) * 256 + w] = packhl(cr);
    if (2 * m + 1 < 258) itw256[(2 * m + 1) * 256 + w] = packhl(ci);
  }
  if (t < 64 * 33) {                         // tw64 [w 64][66]
    int w = t / 33, m = t % 33;
    double th = 2.0 * PI_D * ((m * w) & 63) / 64.0;
    tw64[w * 66 + 2 * m]     = packhl((float)cos(th));
    tw64[w * 66 + 2 * m + 1] = packhl((float)(-sin(th)));
  }
  if (t < 33 * 64) {                         // itw64 [66][64]
    int m = t >> 6, w = t & 63;
    double th = 2.0 * PI_D * ((m * w) & 63) / 64.0;
    float cr, ci;
    if (m == 0)       { cr = 1.f / 64.f; ci = 0.f; }
    else if (m == 32) { cr = ((w & 1) ? -1.f : 1.f) / 64.f; ci = 0.f; }
    else { cr = (float)(2.0 * cos(th) / 64.0); ci = (float)(-2.0 * sin(th) / 64.0); }
    itw64[(2 * m) * 64 + w] = packhl(cr);
    if (2 * m + 1 < 66) itw64[(2 * m + 1) * 64 + w] = packhl(ci);
  }
  if (t < 129 * 64) {                        // iffold [258][64]: irfft256 sampled at w=4*wo
    int m = t >> 6, wo = t & 63;
    double th = 2.0 * PI_D * ((m * wo) & 63) / 64.0;
    float cr, ci;
    if (m == 0)        { cr = 1.f / 256.f; ci = 0.f; }
    else if (m == 128) { cr = 1.f / 256.f; ci = 0.f; }   // cos(pi*4*wo)=1
    else { cr = (float)(2.0 * cos(th) / 256.0); ci = (float)(-2.0 * sin(th) / 256.0); }
    iffold[(2 * m) * 64 + wo] = packhl(cr);
    if (2 * m + 1 < 258) iffold[(2 * m + 1) * 64 + wo] = packhl(ci);
  }
}

// ---------------- split pass: f32 -> packed u32 ----------------
__global__ __launch_bounds__(256) void k_split(const float* __restrict__ in,
                                               u32* __restrict__ out, int n)
{
  for (int i = blockIdx.x * 256 + threadIdx.x; i < n; i += gridDim.x * 256)
    out[i] = packhl(in[i]);
}

// merged [w2|skw] packed weights + combined bias
__global__ __launch_bounds__(256) void k_mergew(const float* __restrict__ w2,
    const float* __restrict__ skw, const float* __restrict__ b2, const float* __restrict__ skb,
    u32* __restrict__ wsp, float* __restrict__ bsum)
{
  int t = blockIdx.x * 256 + threadIdx.x;
  if (t < 4 * 256) bsum[t] = b2[t] + skb[t];
  if (t >= 4 * 256 * 768) return;
  int k = t % 768, o = (t / 768) % 256, i = t / (768 * 256);
  float v = (k < 512) ? w2[((size_t)i * 256 + o) * 512 + k]
                      : skw[((size_t)i * 256 + o) * 256 + (k - 512)];
  wsp[t] = packhl(v);
}

// ---------------- weight transposes ----------------
__global__ void k_gwT_lp(const float* __restrict__ gw, u32* __restrict__ gwTlp)
{
  int idx = blockIdx.x * 256 + threadIdx.x;   // [l][o][c]
  int c = idx & 255, o = (idx >> 8) & 255, l = idx >> 16;
  gwTlp[idx] = packhl(gw[((size_t)o * 256 + c) * 32 + l]);
}

__global__ void k_decT(const float* __restrict__ dw, float* __restrict__ dt)
{
  int idx = blockIdx.x * 256 + threadIdx.x;
  if (idx >= 27 * 256) return;
  int c = idx & 255, ok = idx >> 8;
  int o = ok / 9, k = ok % 9;
  dt[idx] = dw[((size_t)o * 256 + c) * 9 + k];
}

// ---------------- psi-hat builds ----------------
__global__ __launch_bounds__(320) void k_psih_dec(const int* __restrict__ off,
    const float* __restrict__ tab, const float* __restrict__ tc, const float* __restrict__ ts,
    float* __restrict__ psih)
{
  int ho = blockIdx.x, hw = blockIdx.y;
  int hi = ho - 16 + hw;
  int t = threadIdx.x;
  if (t >= 258) return;
  int m = t >> 1, ri = t & 1;
  const float* tw = ri ? ts : tc;
  float acc[9] = {};
  if (hi >= 0 && hi < 128) {
    int e0 = off[ho * 129 + hi], e1 = off[ho * 129 + hi + 1];
    const float* tb = tab + ((size_t)ho * ME_DEC + e0) * 12;
    for (int e = e0; e < e1; ++e, tb += 12) {
      int d = __float_as_int(tb[0]) & 0xffff;
      float v = tw[(m * d) & 255];
#pragma unroll
      for (int k = 0; k < 9; ++k) acc[k] += tb[1 + k] * v;
    }
  }
  size_t base = ((size_t)(ho * 33 + hw) * 9) * 258 + 2 * m + ri;
#pragma unroll
  for (int k = 0; k < 9; ++k) psih[base + (size_t)k * 258] = acc[k];
}

__global__ __launch_bounds__(128) void k_psih_int(const int* __restrict__ off,
    const float* __restrict__ tab, const float* __restrict__ tc, const float* __restrict__ ts,
    float* __restrict__ psih)
{
  int ho = blockIdx.x, hi = blockIdx.y;
  int t = threadIdx.x;
  if (t >= 66) return;
  int m = t >> 1, ri = t & 1;
  const float* tw = ri ? ts : tc;
  float acc[9] = {};
  int e0 = off[ho * 33 + hi], e1 = off[ho * 33 + hi + 1];
  const float* tb = tab + ((size_t)ho * ME_INT + e0) * 12;
  for (int e = e0; e < e1; ++e, tb += 12) {
    int d = __float_as_int(tb[0]) & 0xffff;
    float v = tw[(m * d) & 63];
#pragma unroll
    for (int k = 0; k < 9; ++k) acc[k] += tb[1 + k] * v;
  }
  size_t base = ((size_t)(ho * 32 + hi) * 9) * 66 + 2 * m + ri;
#pragma unroll
  for (int k = 0; k < 9; ++k) psih[base + (size_t)k * 66] = acc[k];
}

__global__ __launch_bounds__(320) void k_psih_enc(const int* __restrict__ off,
    const float* __restrict__ tab, const float* __restrict__ tc, const float* __restrict__ ts,
    float* __restrict__ psih)
{
  int ho = blockIdx.x, hw = blockIdx.y;     // (32, 34)
  int hi = 4 * ho - 15 + hw;
  int t = threadIdx.x;
  if (t >= 258) return;
  int m = t >> 1, ri = t & 1;
  const float* tw = ri ? ts : tc;
  float acc[9] = {};
  if (hi >= 0 && hi < 128) {
    int e0 = off[ho * 129 + hi], e1 = off[ho * 129 + hi + 1];
    const float* tb = tab + ((size_t)ho * ME_ENC + e0) * 12;
    for (int e = e0; e < e1; ++e, tb += 12) {
      int d = __float_as_int(tb[0]) & 0xffff;
      float v = tw[(m * d) & 255];
#pragma unroll
      for (int k = 0; k < 9; ++k) acc[k] += tb[1 + k] * v;
    }
  }
  size_t base = ((size_t)(ho * HW_E + hw) * 9) * 258 + 2 * m + ri;
#pragma unroll
  for (int k = 0; k < 9; ++k) psih[base + (size_t)k * 258] = acc[k];
}

// ---------------- m-space encoder conv ----------------
__global__ __launch_bounds__(192) void k_enc_mconv(const float* __restrict__ psih,
    const float* __restrict__ XhE, float* __restrict__ Zh)
{
  int ho = blockIdx.x, cb = blockIdx.y;     // (32, 24)
  int c = cb >> 3, b = cb & 7;
  int m = threadIdx.x;
  if (m > 128) return;
  const float2* X2 = (const float2*)XhE;
  const float2* P2 = (const float2*)psih;
  float zr[9] = {}, zi[9] = {};
  int hi0 = 4 * ho - 15;
  for (int hw = 0; hw < HW_E; ++hw) {
    int hi = hi0 + hw;
    if (hi < 0 || hi > 127) continue;
    float2 xv = X2[((size_t)(b * 3 + c) * 128 + hi) * 129 + m];
    size_t pb = ((size_t)(ho * HW_E + hw) * 9) * 129 + m;
#pragma unroll
    for (int k = 0; k < 9; ++k) {
      float2 p = P2[pb + (size_t)k * 129];
      zr[k] += p.x * xv.x - p.y * xv.y;
      zi[k] += p.x * xv.y + p.y * xv.x;
    }
  }
#pragma unroll
  for (int k = 0; k < 9; ++k)
    ((float2*)Zh)[(((size_t)(c * 9 + k) * 8 + b) * 32 + ho) * 129 + m] =
        make_float2(zr[k], zi[k]);
}

// ---------------- m-space local conv ----------------
__global__ __launch_bounds__(320) void k_int_mconv(const float* __restrict__ xh,
    const float* __restrict__ psih, float* __restrict__ zh, int c0)
{
  int ho = blockIdx.x, g = blockIdx.y, b = blockIdx.z;  // grid (32, 8, 8)
  int t = threadIdx.x;
  if (t >= 264) return;
  int cl = t / 33, m = t % 33;
  int c = c0 + g * 8 + cl;
  const float2* X2 = (const float2*)xh;
  const float2* P2 = (const float2*)psih;
  float zr[9] = {}, zi[9] = {};
  for (int hi = 0; hi < 32; ++hi) {
    float2 xv = X2[((size_t)(c * 8 + b) * 32 + hi) * 33 + m];
    size_t pb = ((size_t)(ho * 32 + hi) * 9) * 33 + m;
#pragma unroll
    for (int k = 0; k < 9; ++k) {
      float2 p = P2[pb + (size_t)k * 33];
      zr[k] += p.x * xv.x - p.y * xv.y;
      zi[k] += p.x * xv.y + p.y * xv.x;
    }
  }
  int crow = (g * 8 + cl) * 9;
#pragma unroll
  for (int k = 0; k < 9; ++k)
    ((float2*)zh)[((size_t)(crow + k)) * 8448 + b * 1056 + ho * 33 + m] =
        make_float2(zr[k], zi[k]);
}

// ---------------- m-space decoder conv: one block per (ho, m-half), b & o folded in ----------------
// XCD-chunked ho mapping: xcd k (bid.x % 8) owns ho in [16k, 16k+16) -> 48-row G window fits L2.
__global__ __launch_bounds__(96) void k_dec_mconv(const float* __restrict__ psih,
    const float* __restrict__ gh, float* __restrict__ yh)
{
  int bx = blockIdx.x;                      // 128
  int ho = ((bx & 7) << 4) | (bx >> 3);
  int mh = blockIdx.y;                      // 2: m in [0,65) / [65,129)
  int m = mh * 65 + threadIdx.x;
  if (m > 128 || (mh == 0 && threadIdx.x >= 65)) return;
  const float2* P2 = (const float2*)psih;
  const float2* G2 = (const float2*)gh;
  float yr[8][3] = {}, yi[8][3] = {};
  int hw0 = ho >= 16 ? 0 : 16 - ho;
  int hw1 = ho <= 111 ? 33 : 144 - ho;
  for (int hw = hw0; hw < hw1; ++hw) {
    int hi = ho - 16 + hw;
    size_t pb = ((size_t)(ho * 33 + hw) * 9) * 129 + m;
    size_t gb = (size_t)hi * 129 + m;
#pragma unroll
    for (int k = 0; k < 9; ++k) {
      float2 p = P2[pb + (size_t)k * 129];
#pragma unroll
      for (int o = 0; o < 3; ++o) {
        size_t g0 = gb + ((size_t)((o * 9 + k) * 8) * 128) * 129;
#pragma unroll
        for (int b = 0; b < 8; ++b) {
          float2 gv = G2[g0 + ((size_t)b * 128) * 129];
          yr[b][o] += p.x * gv.x - p.y * gv.y;
          yi[b][o] += p.x * gv.y + p.y * gv.x;
        }
      }
    }
  }
#pragma unroll
  for (int b = 0; b < 8; ++b)
#pragma unroll
    for (int o = 0; o < 3; ++o)
      ((float2*)yh)[((size_t)(b * 3 + o) * 128 + ho) * 129 + m] = make_float2(yr[b][o], yi[b][o]);
}

// ---------------- LDS-tiled SHT analysis ----------------
__global__ __launch_bounds__(64) void k_analysis2(const float* __restrict__ PW,
    const float* __restrict__ XH, u32* __restrict__ c1sp)
{
  int c = blockIdx.x, b = blockIdx.y;
  int t = threadIdx.x;                 // q = 2m+ri, 64
  __shared__ float s[32 * 64];         // [h][q]
  __shared__ float pwl[32 * 33];       // [m][h] padded
  const float* xr = XH + ((size_t)(c * 8 + b) * 32) * 66;
  for (int h = 0; h < 32; ++h) s[h * 64 + t] = xr[h * 66 + t];
  int m = t >> 1;
  for (int l = 0; l < 32; ++l) {
    __syncthreads();
#pragma unroll
    for (int j = 0; j < 16; ++j) {
      int idx = t * 16 + j;
      pwl[(idx >> 5) * 33 + (idx & 31)] = PW[(size_t)l * 1024 + idx];
    }
    __syncthreads();
    float acc = 0.f;
#pragma unroll
    for (int h = 0; h < 32; ++h) acc += pwl[m * 33 + h] * s[h * 64 + t];
    c1sp[(size_t)l * 131072 + c * 512 + b * 64 + t] = packhl(acc);
  }
}

// ---------------- LDS-tiled SHT synthesis ----------------
__global__ __launch_bounds__(64) void k_synth2(const float* __restrict__ PT,
    const float* __restrict__ c2s, float* __restrict__ Xo)
{
  int o = blockIdx.x, b = blockIdx.y;
  int t = threadIdx.x;                 // q
  __shared__ float s2[32 * 64];        // [l][q]
  __shared__ float ptl[32 * 33];       // [m][h] padded
  for (int l = 0; l < 32; ++l)
    s2[l * 64 + t] = c2s[((size_t)(l * 256 + o)) * 512 + b * 64 + t];
  int m = t >> 1;
  float acc[32];
#pragma unroll
  for (int h = 0; h < 32; ++h) acc[h] = 0.f;
  for (int l = 0; l < 32; ++l) {
    __syncthreads();
#pragma unroll
    for (int j = 0; j < 16; ++j) {
      int idx = t * 16 + j;
      ptl[(idx >> 5) * 33 + (idx & 31)] = PT[(size_t)l * 1024 + idx];
    }
    __syncthreads();
    float sv = s2[l * 64 + t];
#pragma unroll
    for (int h = 0; h < 32; ++h) acc[h] += ptl[m * 33 + h] * sv;
  }
  size_t base = ((size_t)(o * 8 + b) * 32) * 64 + t;
#pragma unroll
  for (int h = 0; h < 32; ++h) Xo[base + (size_t)h * 64] = acc[h];
}

// ---------------- MFMA f16x3 split GEMM ----------------
__global__ __launch_bounds__(256) void k_gemm(
    int M, int N, int K,
    const float* __restrict__ A, const u32* __restrict__ Ap, int lda, long long sA,
    const float* __restrict__ Bm, const u32* __restrict__ Bp, int ldb, long long sB,
    float* __restrict__ C, int ldc, long long sC, u32* __restrict__ Cp,
    const float* __restrict__ bias, int flags)
{
  if (A)  A  += (size_t)blockIdx.z * sA;
  if (Ap) Ap += (size_t)blockIdx.z * sA;
  if (Bm) Bm += (size_t)blockIdx.z * sB;
  if (Bp) Bp += (size_t)blockIdx.z * sB;
  if (C)  C  += (size_t)blockIdx.z * sC;
  if (Cp) Cp += (size_t)blockIdx.z * sC;
  __shared__ alignas(16) u16 Ah[128 * 36], Al[128 * 36], Bh[128 * 36], Bl[128 * 36];
  int bm = blockIdx.y * 128, bn = blockIdx.x * 128;
  int tid = threadIdx.x;
  int sr = tid >> 1, k2 = tid & 1;
  int lane = tid & 63, wid = tid >> 6;
  int wr = wid >> 1, wc = wid & 1;
  int lrow = lane & 15, kg = lane >> 4;
  f32x4 acc[4][4] = {};
  bool bok = (bn + sr) < N;

  for (int k0 = 0; k0 < K; k0 += 32) {
    {  // stage A
      u32* ph = (u32*)&Ah[sr * 36 + k2 * 16];
      u32* pl = (u32*)&Al[sr * 36 + k2 * 16];
      if (Ap) {
        const u32* Ar = Ap + (size_t)(bm + sr) * lda + k0 + k2 * 16;
#pragma unroll
        for (int j2 = 0; j2 < 8; ++j2) {
          int gk = k0 + k2 * 16 + 2 * j2;
          u32 w0 = (gk < K)     ? Ar[2 * j2]     : 0u;
          u32 w1 = (gk + 1 < K) ? Ar[2 * j2 + 1] : 0u;
          ph[j2] = (w0 & 0xffffu) | (w1 << 16);
          pl[j2] = (w0 >> 16) | (w1 & 0xffff0000u);
        }
      } else {
        const float* Ar = A + (size_t)(bm + sr) * lda + k0 + k2 * 16;
#pragma unroll
        for (int j2 = 0; j2 < 8; ++j2) {
          int gk = k0 + k2 * 16 + 2 * j2;
          float v0 = (gk < K)     ? Ar[2 * j2]     : 0.f;
          float v1 = (gk + 1 < K) ? Ar[2 * j2 + 1] : 0.f;
          u16 h0 = f16rne(v0), h1 = f16rne(v1);
          u16 l0 = f16rne(v0 - f16tof(h0)), l1 = f16rne(v1 - f16tof(h1));
          ph[j2] = (u32)h0 | ((u32)h1 << 16);
          pl[j2] = (u32)l0 | ((u32)l1 << 16);
        }
      }
    }
    {  // stage B (transpose K-major -> [n][k])
      u32* ph = (u32*)&Bh[sr * 36 + k2 * 16];
      u32* pl = (u32*)&Bl[sr * 36 + k2 * 16];
      if (Bp) {
        const u32* Bc = Bp + bn + sr;
#pragma unroll
        for (int j2 = 0; j2 < 8; ++j2) {
          int gk = k0 + k2 * 16 + 2 * j2;
          u32 w0 = (bok && gk < K)     ? Bc[(size_t)gk * ldb]       : 0u;
          u32 w1 = (bok && gk + 1 < K) ? Bc[(size_t)(gk + 1) * ldb] : 0u;
          ph[j2] = (w0 & 0xffffu) | (w1 << 16);
          pl[j2] = (w0 >> 16) | (w1 & 0xffff0000u);
        }
      } else {
        const float* Bc = Bm + bn + sr;
#pragma unroll
        for (int j2 = 0; j2 < 8; ++j2) {
          int gk = k0 + k2 * 16 + 2 * j2;
          float v0 = (bok && gk < K)     ? Bc[(size_t)gk * ldb]       : 0.f;
          float v1 = (bok && gk + 1 < K) ? Bc[(size_t)(gk + 1) * ldb] : 0.f;
          u16 h0 = f16rne(v0), h1 = f16rne(v1);
          u16 l0 = f16rne(v0 - f16tof(h0)), l1 = f16rne(v1 - f16tof(h1));
          ph[j2] = (u32)h0 | ((u32)h1 << 16);
          pl[j2] = (u32)l0 | ((u32)l1 << 16);
        }
      }
    }
    __syncthreads();
    f16x8 fah[4], fal[4], fbh[4], fbl[4];
#pragma unroll
    for (int i = 0; i < 4; ++i) {
      int ar = wr * 64 + i * 16 + lrow;
      fah[i] = *(const f16x8*)&Ah[ar * 36 + kg * 8];
      fal[i] = *(const f16x8*)&Al[ar * 36 + kg * 8];
      int br = wc * 64 + i * 16 + lrow;
      fbh[i] = *(const f16x8*)&Bh[br * 36 + kg * 8];
      fbl[i] = *(const f16x8*)&Bl[br * 36 + kg * 8];
    }
#pragma unroll
    for (int i = 0; i < 4; ++i)
#pragma unroll
      for (int j = 0; j < 4; ++j) {
        acc[i][j] = __builtin_amdgcn_mfma_f32_16x16x32_f16(fah[i], fbh[j], acc[i][j], 0, 0, 0);
        acc[i][j] = __builtin_amdgcn_mfma_f32_16x16x32_f16(fah[i], fbl[j], acc[i][j], 0, 0, 0);
        acc[i][j] = __builtin_amdgcn_mfma_f32_16x16x32_f16(fal[i], fbh[j], acc[i][j], 0, 0, 0);
      }
    __syncthreads();
  }

#pragma unroll
  for (int i = 0; i < 4; ++i) {
    int gm0 = bm + wr * 64 + i * 16 + kg * 4;
#pragma unroll
    for (int j = 0; j < 4; ++j) {
      int gn = bn + wc * 64 + j * 16 + lrow;
      if (gn >= N) continue;
#pragma unroll
      for (int rr = 0; rr < 4; ++rr) {
        int gm = gm0 + rr;
        size_t idx = (size_t)gm * ldc + gn;
        float v = acc[i][j][rr];
        if (flags & 4) v += bias[gm];
        if (flags & 2) v += C[idx];
        if (flags & 1) v = fmaxf(v, 0.f);
        if (C) C[idx] = v;
        if (flags & 8) Cp[idx] = packhl(v);
      }
    }
  }
}

// small-M GEMM: M=27, K=256, N=16384 (decoder channel mix)
__global__ __launch_bounds__(256) void k_gemm_m27(const float* __restrict__ A,
    const float* __restrict__ Bm, float* __restrict__ C)
{
  int n = blockIdx.x * 256 + threadIdx.x;
  float acc[27] = {};
  for (int k = 0; k < 256; ++k) {
    float bv = Bm[(size_t)k * NSP + n];
#pragma unroll
    for (int m = 0; m < 27; ++m) acc[m] += A[m * 256 + k] * bv;
  }
#pragma unroll
  for (int m = 0; m < 27; ++m) C[(size_t)m * NSP + n] = acc[m];
}

// ---------------- bilinear resample (32,64) -> (128,256), channel-major ----------------
__global__ __launch_bounds__(256) void k_resample(const float* __restrict__ gi, float* __restrict__ gf)
{
  int t = blockIdx.x * 256 + threadIdx.x;
  int WO = t & 255, HO = (t >> 8) & 127, b = (t >> 15) & 7, ok = t >> 18;
  float fi = fminf(fmaxf(HO * 0.25f - 0.375f, 0.f), 31.f);
  int i0 = (int)fi;
  int i1 = min(i0 + 1, 31);
  float wi = fi - (float)i0;
  int j0 = WO >> 2;
  int j1 = (j0 + 1) & 63;
  float wj = (float)(WO & 3) * 0.25f;
  const float* s = gi + (size_t)ok * NSP + b * 2048;
  float v00 = s[i0 * 64 + j0], v01 = s[i0 * 64 + j1];
  float v10 = s[i1 * 64 + j0], v11 = s[i1 * 64 + j1];
  float a0 = v00 * (1.f - wj) + v01 * wj;
  float a1 = v10 * (1.f - wj) + v11 * wj;
  gf[((size_t)ok * 8 + b) * 32768 + HO * 256 + WO] = a0 * (1.f - wi) + a1 * wi;
}

} // namespace

extern "C" void kernel_launch(void* const* d_in, const int* in_sizes, int n_in,
                              void* d_out, int out_size, void* d_ws, size_t ws_size,
                              hipStream_t stream)
{
  const float* x_in  = (const float*)d_in[0];
  const float* enc_w = (const float*)d_in[1];
  const float* lconv = (const float*)d_in[2];
  const float* gconv = (const float*)d_in[3];
  const float* w1    = (const float*)d_in[4];
  const float* b1    = (const float*)d_in[5];
  const float* w2    = (const float*)d_in[6];
  const float* b2    = (const float*)d_in[7];
  const float* skw   = (const float*)d_in[8];
  const float* skb   = (const float*)d_in[9];
  const float* decw  = (const float*)d_in[10];
  float* out = (float*)d_out;

  char* ws = (char*)d_ws;
  size_t off = 0;
  auto alloc = [&](size_t nfloats) -> float* {
    float* p = (float*)(ws + off);
    off += ((nfloats * 4 + 255) / 256) * 256;
    return p;
  };
  float* PW    = alloc(32768);
  float* PT    = alloc(32768);
  float* tc256 = alloc(256);
  float* ts256 = alloc(256);
  float* tc64  = alloc(64);
  float* ts64  = alloc(64);
  u32* TW256p  = (u32*)alloc(256 * 258);
  u32* ITW256p = (u32*)alloc(258 * 256);
  u32* TW64p   = (u32*)alloc(64 * 66);
  u32* ITW64p  = (u32*)alloc(66 * 64);
  u32* IFp     = (u32*)alloc(258 * 64);
  int*   cnt2  = (int*)alloc(21504);
  int*   cnt_enc = cnt2;
  int*   cnt_int = cnt2 + 4096;
  int*   cnt_dec = cnt2 + 5120;
  int*   off_enc = (int*)alloc(32 * 129);
  int*   off_int = (int*)alloc(32 * 33);
  int*   off_dec = (int*)alloc(128 * 129);
  float* decT     = alloc(27 * 256);
  float* psih_dec = alloc((size_t)128 * 33 * 9 * 258);   // 39.2 MB
  float* psih_int = alloc((size_t)32 * 32 * 9 * 66);     // 2.4 MB
  float* psih_enc = alloc((size_t)32 * HW_E * 9 * 258);  // 10.1 MB
  u32* enc_wp = (u32*)alloc(256 * 27);
  u32* w1p    = (u32*)alloc(4 * 512 * 256);
  u32* wsp    = (u32*)alloc(4 * 256 * 768);              // merged [w2|skw] packed
  float* bsum = alloc(4 * 256);
  u32* lconvp = (u32*)alloc(2 * 256 * 2304);
  float* P  = alloc((size_t)EE * NSP);
  float* Q  = alloc((size_t)EE * NSP);
  float* T  = alloc((size_t)EE * NSP);
  u32*   Tp = (u32*)alloc((size_t)EE * NSP);             // packed T (16.8 MB)
  float* U  = alloc(19005440);                           // 76 MB phase-union scratch
  (void)ws_size; (void)in_sizes; (void)n_in; (void)out_size;

  // phase-local aliases inside U (float offsets)
  float* tab_dec = U;                          // setup: 7,077,888
  float* tab_int = U + 7077888;                // setup:   786,432
  float* tab_enc = U + 7864320;                // setup: 1,966,080
  float* zc      = U;                          // encoder:  442,368
  float* XhE     = U + 442368;                 // encoder:  792,576
  float* ZhE     = U + 1234944;                // encoder: 1,783,296
  float* XH      = U;                          // local: 4,325,376
  float* ZH      = U + 4325376;                // local: 9,732,096
  float* XO      = U + 14057472;               // local: 4,325,376
  u32*   gwTlp   = (u32*)U;                    // spectral: 2,097,152 u32
  u32*   c1sp    = (u32*)(U + 2097152);        // spectral: 4,194,304 u32
  float* c2s     = U + 6291456;                // spectral: 4,194,304 f32
  float* Xo_s    = U + 10485760;               // spectral: 4,194,304 f32
  float* XHs     = U + 14680064;               // spectral: 4,325,376 f32
  u32*   Hbp     = (u32*)U;                    // MLP: 8,388,608 u32 (rows 0..511)
  u32*   Pp      = (u32*)(U + 8388608);        // MLP: 4,194,304 u32 (rows 512..767, contiguous!)
  float* g_int   = U;                          // dec:   442,368
  float* g_full  = U + 524288;                 // dec: 7,077,888
  float* GH      = U + 7602176;                // dec: 7,133,184
  float* YH      = U + 14735360;               // dec:   792,576

  const double CUT_LOC = 4.0 * PI_D / 31.0;
  const double CUT_INT = 16.0 * PI_D / 31.0;
  auto splitN = [&](const float* src, u32* dst, int n) {
    int g = (n + 255) / 256; if (g > 2048) g = 2048;
    hipLaunchKernelGGL(k_split, dim3(g), dim3(256), 0, stream, src, dst, n);
  };
  const float* F0 = nullptr; const u32* U0 = nullptr; u32* W0 = nullptr;

  // ---- constants ----
  hipMemsetAsync(cnt2, 0, 21504 * 4, stream);
  hipLaunchKernelGGL(k_legendre, dim3(1), dim3(64), 0, stream, PW, PT);
  hipLaunchKernelGGL(k_tw2, dim3(1), dim3(256), 0, stream, tc256, ts256, tc64, ts64);
  hipLaunchKernelGGL(k_twmat, dim3(129), dim3(256), 0, stream, TW256p, ITW256p, TW64p, ITW64p, IFp);
  hipLaunchKernelGGL(k_decT, dim3(27), dim3(256), 0, stream, decw, decT);
  splitN(enc_w, enc_wp, 256 * 27);
  splitN(w1,    w1p,    4 * 512 * 256);
  hipLaunchKernelGGL(k_mergew, dim3(3072), dim3(256), 0, stream, w2, skw, b2, skb, wsp, bsum);
  splitN(lconv, lconvp, 2 * 256 * 2304);

  hipLaunchKernelGGL(k_psi_count, dim3(128, 32), dim3(256), 0, stream, 128, 256, 32, CUT_LOC, cnt_enc);
  hipLaunchKernelGGL(k_psi_scan,  dim3(32), dim3(1), 0, stream, 128, ME_ENC, cnt_enc, off_enc);
  hipLaunchKernelGGL(k_psi_fill,  dim3(128, 32), dim3(256), 0, stream, 128, 256, 32, CUT_LOC, ME_ENC, cnt_enc, off_enc, tab_enc);

  hipLaunchKernelGGL(k_psi_count, dim3(32, 32), dim3(64), 0, stream, 32, 64, 32, CUT_INT, cnt_int);
  hipLaunchKernelGGL(k_psi_scan,  dim3(32), dim3(1), 0, stream, 32, ME_INT, cnt_int, off_int);
  hipLaunchKernelGGL(k_psi_fill,  dim3(32, 32), dim3(64), 0, stream, 32, 64, 32, CUT_INT, ME_INT, cnt_int, off_int, tab_int);

  hipLaunchKernelGGL(k_psi_count, dim3(128, 128), dim3(256), 0, stream, 128, 256, 128, CUT_LOC, cnt_dec);
  hipLaunchKernelGGL(k_psi_scan,  dim3(128), dim3(1), 0, stream, 128, ME_DEC, cnt_dec, off_dec);
  hipLaunchKernelGGL(k_psi_fill,  dim3(128, 128), dim3(256), 0, stream, 128, 256, 128, CUT_LOC, ME_DEC, cnt_dec, off_dec, tab_dec);

  hipLaunchKernelGGL(k_psih_dec, dim3(128, 33), dim3(320), 0, stream, off_dec, tab_dec, tc256, ts256, psih_dec);
  hipLaunchKernelGGL(k_psih_int, dim3(32, 32),  dim3(128), 0, stream, off_int, tab_int, tc64, ts64, psih_int);
  hipLaunchKernelGGL(k_psih_enc, dim3(32, HW_E), dim3(320), 0, stream, off_enc, tab_enc, tc256, ts256, psih_enc);

  // ---- encoder in m-space: rfft256(x) -> mconv -> folded irfft (stride 4) -> channel mix ----
  hipLaunchKernelGGL(k_gemm, dim3(3, 24, 1), dim3(256), 0, stream,
                     3072, 258, 256, x_in, U0, 256, 0LL, F0, TW256p, 258, 0LL,
                     XhE, 258, 0LL, W0, F0, 0);
  hipLaunchKernelGGL(k_enc_mconv, dim3(32, 24), dim3(192), 0, stream, psih_enc, XhE, ZhE);
  hipLaunchKernelGGL(k_gemm, dim3(1, 54, 1), dim3(256), 0, stream,
                     6912, 64, 258, ZhE, U0, 258, 0LL, F0, IFp, 64, 0LL,
                     zc, 64, 0LL, W0, F0, 0);
  hipLaunchKernelGGL(k_gemm, dim3(128, 2, 1), dim3(256), 0, stream,
                     256, NSP, 27, F0, enc_wp, 27, 0LL, zc, U0, NSP, 0LL,
                     P, NSP, 0LL, W0, F0, 0);

  // ---- 4 blocks ----
  for (int i = 0; i < 4; ++i) {
    int layer = i >> 1;
    if ((i & 1) == 0) {
      // local DISCO block in m-space
      hipLaunchKernelGGL(k_gemm, dim3(1, 512, 1), dim3(256), 0, stream,
                         65536, 66, 64, P, U0, 64, 0LL, F0, TW64p, 66, 0LL,
                         XH, 66, 0LL, W0, F0, 0);
      for (int cc = 0; cc < 4; ++cc) {
        hipLaunchKernelGGL(k_int_mconv, dim3(32, 8, 8), dim3(320), 0, stream,
                           XH, psih_int, ZH, cc * 64);
        hipLaunchKernelGGL(k_gemm, dim3(132, 2, 1), dim3(256), 0, stream,
                           256, 16896, 576,
                           F0, lconvp + (size_t)layer * 589824 + cc * 576, 2304, 0LL,
                           ZH, U0, 16896, 0LL,
                           XO, 16896, 0LL, W0, F0, cc ? 2 : 0);
      }
      hipLaunchKernelGGL(k_gemm, dim3(1, 512, 1), dim3(256), 0, stream,
                         65536, 64, 66, XO, U0, 66, 0LL, F0, ITW64p, 64, 0LL,
                         T, 64, 0LL, Tp, F0, 8);
    } else {
      // spectral (SHT) block: rfft GEMM -> analysis2 -> gconv GEMM -> synth2 -> irfft GEMM
      hipLaunchKernelGGL(k_gwT_lp, dim3(8192), dim3(256), 0, stream,
                         gconv + (size_t)layer * 2097152, gwTlp);
      hipLaunchKernelGGL(k_gemm, dim3(1, 512, 1), dim3(256), 0, stream,
                         65536, 66, 64, P, U0, 64, 0LL, F0, TW64p, 66, 0LL,
                         XHs, 66, 0LL, W0, F0, 0);
      hipLaunchKernelGGL(k_analysis2, dim3(256, 8), dim3(64), 0, stream, PW, XHs, c1sp);
      hipLaunchKernelGGL(k_gemm, dim3(4, 2, 32), dim3(256), 0, stream,
                         256, 512, 256,
                         F0, gwTlp, 256, 65536LL, F0, c1sp, 512, 131072LL,
                         c2s, 512, 131072LL, W0, F0, 0);
      hipLaunchKernelGGL(k_synth2, dim3(256, 8), dim3(64), 0, stream, PT, c2s, Xo_s);
      hipLaunchKernelGGL(k_gemm, dim3(1, 512, 1), dim3(256), 0, stream,
                         65536, 64, 64, Xo_s, U0, 64, 0LL, F0, ITW64p, 64, 0LL,
                         T, 64, 0LL, Tp, F0, 8);
    }
    // MLP + linear skip as ONE merged GEMM:  Q = [w2|skw]·[relu(w1·T+b1); P] + (b2+skb)
    hipLaunchKernelGGL(k_gemm, dim3(128, 4, 1), dim3(256), 0, stream,
                       512, NSP, 256, F0, w1p + (size_t)i * 131072, 256, 0LL,
                       F0, Tp, NSP, 0LL,
                       (float*)nullptr, NSP, 0LL, Hbp, b1 + (size_t)i * 512, 1 | 4 | 8);
    splitN(P, Pp, EE * NSP);
    hipLaunchKernelGGL(k_gemm, dim3(128, 2, 1), dim3(256), 0, stream,
                       256, NSP, 768, F0, wsp + (size_t)i * 196608, 768, 0LL,
                       F0, Hbp, NSP, 0LL,
                       Q, NSP, 0LL, W0, bsum + (size_t)i * 256, 4);
    std::swap(P, Q);
  }

  // ---- decoder: mix E->27, resample, m-space conv (DFTs as GEMMs) ----
  hipLaunchKernelGGL(k_gemm_m27, dim3(64), dim3(256), 0, stream, decT, P, g_int);
  hipLaunchKernelGGL(k_resample, dim3(27648), dim3(256), 0, stream, g_int, g_full);
  hipLaunchKernelGGL(k_gemm, dim3(3, 216, 1), dim3(256), 0, stream,
                     27648, 258, 256, g_full, U0, 256, 0LL, F0, TW256p, 258, 0LL,
                     GH, 258, 0LL, W0, F0, 0);
  hipLaunchKernelGGL(k_dec_mconv, dim3(128, 2), dim3(96), 0, stream, psih_dec, GH, YH);
  hipLaunchKernelGGL(k_gemm, dim3(2, 24, 1), dim3(256), 0, stream,
                     3072, 256, 258, YH, U0, 258, 0LL, F0, ITW256p, 256, 0LL,
                     out, 256, 0LL, W0, F0, 0);
}

// Round 9
// 4523.240 us; speedup vs baseline: 1.0609x; 1.0609x over previous
//
#include <hip/hip_runtime.h>
#include <math.h>
#include <utility>

#define DI __device__ __forceinline__

namespace {

typedef unsigned short u16;
typedef unsigned int u32;
using f16x8 = __attribute__((ext_vector_type(8))) _Float16;
using f32x4 = __attribute__((ext_vector_type(4))) float;

constexpr int BB  = 8;
constexpr int CIN = 3;
constexpr int HIN = 128, WIN = 256;
constexpr int EE  = 256;
constexpr int NSP = BB * 32 * 64;   // 16384
constexpr double PI_D = 3.14159265358979323846;
constexpr int ME_ENC = 5120, ME_INT = 2048, ME_DEC = 4608;
constexpr int HW_E = 34;            // encoder hi-window rows per ho

DI u16 f16rne(float x) { _Float16 h = (_Float16)x; return __builtin_bit_cast(unsigned short, h); }
DI float f16tof(u16 u) { return (float)__builtin_bit_cast(_Float16, u); }
DI u32 packhl(float v) {
  u16 h = f16rne(v);
  u16 l = f16rne(v - f16tof(h));
  return (u32)h | ((u32)l << 16);
}

// ---------------- psi evaluation (double, matches numpy f64 build) ----------------
DI bool psi_point(int nlat_in, int nlon_in, int nlat_out, double cutoff,
                  int ho, int hi, int d, bool wantv, float* out9)
{
  double ti = PI_D * (hi + 0.5) / nlat_in;
  double to = PI_D * (ho + 0.5) / nlat_out;
  double ph = 2.0 * PI_D * d / nlon_in;
  double cto = cos(to), sto = sin(to);
  double cti = cos(ti), sti = sin(ti);
  double cph = cos(ph), sph = sin(ph);
  double ca = cto * cti + sto * sti * cph;
  ca = fmin(1.0, fmax(-1.0, ca));
  double r = acos(ca);
  if (r > cutoff) return false;
  if (wantv) {
    double dr   = cutoff * 0.5;
    double dphi = PI_D * 0.5;
    double quad = sti * (PI_D / nlat_in) * (2.0 * PI_D / nlon_in);
    out9[0] = (float)(fmin(1.0, fmax(0.0, 1.0 - r / dr)) * quad);
    double alpha = atan2(sti * sph, cti * sto - sti * cto * cph);
#pragma unroll
    for (int j = 1; j <= 2; ++j) {
      double tr = fmin(1.0, fmax(0.0, 1.0 - fabs(r - j * dr) / dr));
#pragma unroll
      for (int k2 = 0; k2 < 4; ++k2) {
        double xx = alpha - k2 * dphi + PI_D;
        double yy = xx - 2.0 * PI_D * floor(xx / (2.0 * PI_D));
        double dd = fabs(yy - PI_D);
        out9[1 + (j - 1) * 4 + k2] = (float)(tr * fmin(1.0, fmax(0.0, 1.0 - dd / dphi)) * quad);
      }
    }
  }
  return true;
}

__global__ void k_psi_count(int nlat_in, int nlon_in, int nlat_out, double cutoff, int* cnt)
{
  int hi = blockIdx.x, ho = blockIdx.y, d = threadIdx.x;
  float dummy[9];
  bool in = psi_point(nlat_in, nlon_in, nlat_out, cutoff, ho, hi, d, false, dummy);
  unsigned long long mask = __ballot(in);
  if ((threadIdx.x & 63) == 0) {
    int tot = __popcll(mask);
    if (tot) atomicAdd(cnt + ho * nlat_in + hi, tot);
  }
}

__global__ void k_psi_scan(int nlat_in, int maxe, int* cnt, int* offs)
{
  int ho = blockIdx.x;
  int* c = cnt + ho * nlat_in;
  int* o = offs + ho * (nlat_in + 1);
  int run = 0;
  for (int hi = 0; hi < nlat_in; ++hi) {
    o[hi] = run < maxe ? run : maxe;
    run += c[hi];
    c[hi] = 0;
  }
  o[nlat_in] = run < maxe ? run : maxe;
}

__global__ void k_psi_fill(int nlat_in, int nlon_in, int nlat_out, double cutoff,
                           int maxe, int* cnt, const int* __restrict__ offs, float* __restrict__ tab)
{
  int hi = blockIdx.x, ho = blockIdx.y, d = threadIdx.x;
  float p9[9];
  bool in = psi_point(nlat_in, nlon_in, nlat_out, cutoff, ho, hi, d, true, p9);
  unsigned long long mask = __ballot(in);
  int lane = threadIdx.x & 63;
  int tot = __popcll(mask);
  int wbase = 0;
  if (lane == 0 && tot) wbase = atomicAdd(cnt + ho * nlat_in + hi, tot);
  wbase = __shfl(wbase, 0, 64);
  if (in) {
    int rank = __popcll(mask & ((1ull << lane) - 1ull));
    int idx = offs[ho * (nlat_in + 1) + hi] + wbase + rank;
    if (idx < maxe) {
      float* te = tab + ((size_t)ho * maxe + idx) * 12;
      te[0] = __int_as_float((hi << 16) | d);
#pragma unroll
      for (int k = 0; k < 9; ++k) te[1 + k] = p9[k];
      te[10] = 0.f; te[11] = 0.f;
    }
  }
}

// ---------------- Legendre PW/PT + twiddles ----------------
__global__ void k_legendre(float* __restrict__ PW, float* __restrict__ PT)
{
  int h = threadIdx.x;
  if (h >= 32) return;
  double th = PI_D * (h + 0.5) / 32.0;
  double ct = cos(th), st = sin(th);
  double quad = st * (PI_D / 32.0);
  double diag = 0.70710678118654752440;
  for (int m = 0; m < 32; ++m) {
    if (m > 0) diag = sqrt((2.0 * m + 1.0) / (2.0 * m)) * st * diag;
    double plm2 = diag;
    PT[((size_t)m * 32 + m) * 32 + h] = (float)plm2;
    PW[((size_t)m * 32 + m) * 32 + h] = (float)(plm2 * quad);
    if (m + 1 < 32) {
      double plm1 = sqrt(2.0 * m + 3.0) * ct * diag;
      PT[((size_t)(m + 1) * 32 + m) * 32 + h] = (float)plm1;
      PW[((size_t)(m + 1) * 32 + m) * 32 + h] = (float)(plm1 * quad);
      for (int l = m + 2; l < 32; ++l) {
        double a  = sqrt((4.0 * l * l - 1.0) / ((double)l * l - (double)m * m));
        double bb = a * sqrt((((double)(l - 1) * (l - 1)) - (double)m * m) /
                             (4.0 * (double)(l - 1) * (l - 1) - 1.0));
        double p = a * ct * plm1 - bb * plm2;
        PT[((size_t)l * 32 + m) * 32 + h] = (float)p;
        PW[((size_t)l * 32 + m) * 32 + h] = (float)(p * quad);
        plm2 = plm1; plm1 = p;
      }
    }
    for (int l = 0; l < m; ++l) {
      PT[((size_t)l * 32 + m) * 32 + h] = 0.f;
      PW[((size_t)l * 32 + m) * 32 + h] = 0.f;
    }
  }
}

__global__ void k_tw2(float* tc256, float* ts256, float* tc64, float* ts64)
{
  int t = threadIdx.x;
  double th = 2.0 * PI_D * t / 256.0;
  tc256[t] = (float)cos(th);
  ts256[t] = (float)sin(th);
  if (t < 64) {
    double th2 = 2.0 * PI_D * t / 64.0;
    tc64[t] = (float)cos(th2);
    ts64[t] = (float)sin(th2);
  }
}

// twiddle MATRICES for DFT-as-GEMM, pre-split packed u32 (f16hi | f16lo<<16)
__global__ void k_twmat(u32* __restrict__ tw256, u32* __restrict__ itw256,
                        u32* __restrict__ tw64, u32* __restrict__ itw64,
                        u32* __restrict__ iffold)
{
  int t = blockIdx.x * 256 + threadIdx.x;
  if (t < 256 * 129) {                       // tw256 [w 256][258]
    int w = t / 129, m = t % 129;
    double th = 2.0 * PI_D * ((m * w) & 255) / 256.0;
    tw256[w * 258 + 2 * m]     = packhl((float)cos(th));
    tw256[w * 258 + 2 * m + 1] = packhl((float)(-sin(th)));
  }
  if (t < 129 * 256) {                       // itw256 [258][256]
    int m = t >> 8, w = t & 255;
    double th = 2.0 * PI_D * ((m * w) & 255) / 256.0;
    float cr, ci;
    if (m == 0)        { cr = 1.f / 256.f; ci = 0.f; }
    else if (m == 128) { cr = ((w & 1) ? -1.f : 1.f) / 256.f; ci = 0.f; }
    else { cr = (float)(2.0 * cos(th) / 256.0); ci = (float)(-2.0 * sin(th) / 256.0); }
    itw256[(2 * m) * 256 + w] = packhl(cr);
    if (2 * m + 1 < 258) itw256[(2 * m + 1) * 256 + w] = packhl(ci);
  }
  if (t < 64 * 33) {                         // tw64 [w 64][66]
    int w = t / 33, m = t % 33;
    double th = 2.0 * PI_D * ((m * w) & 63) / 64.0;
    tw64[w * 66 + 2 * m]     = packhl((float)cos(th));
    tw64[w * 66 + 2 * m + 1] = packhl((float)(-sin(th)));
  }
  if (t < 33 * 64) {                         // itw64 [66][64]
    int m = t >> 6, w = t & 63;
    double th = 2.0 * PI_D * ((m * w) & 63) / 64.0;
    float cr, ci;
    if (m == 0)       { cr = 1.f / 64.f; ci = 0.f; }
    else if (m == 32) { cr = ((w & 1) ? -1.f : 1.f) / 64.f; ci = 0.f; }
    else { cr = (float)(2.0 * cos(th) / 64.0); ci = (float)(-2.0 * sin(th) / 64.0); }
    itw64[(2 * m) * 64 + w] = packhl(cr);
    if (2 * m + 1 < 66) itw64[(2 * m + 1) * 64 + w] = packhl(ci);
  }
  if (t < 129 * 64) {                        // iffold [258][64]: irfft256 sampled at w=4*wo
    int m = t >> 6, wo = t & 63;
    double th = 2.0 * PI_D * ((m * wo) & 63) / 64.0;
    float cr, ci;
    if (m == 0)        { cr = 1.f / 256.f; ci = 0.f; }
    else if (m == 128) { cr = 1.f / 256.f; ci = 0.f; }   // cos(pi*4*wo)=1
    else { cr = (float)(2.0 * cos(th) / 256.0); ci = (float)(-2.0 * sin(th) / 256.0); }
    iffold[(2 * m) * 64 + wo] = packhl(cr);
    if (2 * m + 1 < 258) iffold[(2 * m + 1) * 64 + wo] = packhl(ci);
  }
}

// ---------------- split pass: f32 -> packed u32 ----------------
__global__ __launch_bounds__(256) void k_split(const float* __restrict__ in,
                                               u32* __restrict__ out, int n)
{
  for (int i = blockIdx.x * 256 + threadIdx.x; i < n; i += gridDim.x * 256)
    out[i] = packhl(in[i]);
}

// merged [w2|skw] packed weights + combined bias
__global__ __launch_bounds__(256) void k_mergew(const float* __restrict__ w2,
    const float* __restrict__ skw, const float* __restrict__ b2, const float* __restrict__ skb,
    u32* __restrict__ wsp, float* __restrict__ bsum)
{
  int t = blockIdx.x * 256 + threadIdx.x;
  if (t < 4 * 256) bsum[t] = b2[t] + skb[t];
  if (t >= 4 * 256 * 768) return;
  int k = t % 768, o = (t / 768) % 256, i = t / (768 * 256);
  float v = (k < 512) ? w2[((size_t)i * 256 + o) * 512 + k]
                      : skw[((size_t)i * 256 + o) * 256 + (k - 512)];
  wsp[t] = packhl(v);
}

// ---------------- weight transposes ----------------
__global__ void k_gwT_lp(const float* __restrict__ gw, u32* __restrict__ gwTlp)
{
  int idx = blockIdx.x * 256 + threadIdx.x;   // [l][o][c]
  int c = idx & 255, o = (idx >> 8) & 255, l = idx >> 16;
  gwTlp[idx] = packhl(gw[((size_t)o * 256 + c) * 32 + l]);
}

__global__ void k_decT(const float* __restrict__ dw, float* __restrict__ dt)
{
  int idx = blockIdx.x * 256 + threadIdx.x;
  if (idx >= 27 * 256) return;
  int c = idx & 255, ok = idx >> 8;
  int o = ok / 9, k = ok % 9;
  dt[idx] = dw[((size_t)o * 256 + c) * 9 + k];
}

// ---------------- psi-hat builds ----------------
__global__ __launch_bounds__(320) void k_psih_dec(const int* __restrict__ off,
    const float* __restrict__ tab, const float* __restrict__ tc, const float* __restrict__ ts,
    float* __restrict__ psih)
{
  int ho = blockIdx.x, hw = blockIdx.y;
  int hi = ho - 16 + hw;
  int t = threadIdx.x;
  if (t >= 258) return;
  int m = t >> 1, ri = t & 1;
  const float* tw = ri ? ts : tc;
  float acc[9] = {};
  if (hi >= 0 && hi < 128) {
    int e0 = off[ho * 129 + hi], e1 = off[ho * 129 + hi + 1];
    const float* tb = tab + ((size_t)ho * ME_DEC + e0) * 12;
    for (int e = e0; e < e1; ++e, tb += 12) {
      int d = __float_as_int(tb[0]) & 0xffff;
      float v = tw[(m * d) & 255];
#pragma unroll
      for (int k = 0; k < 9; ++k) acc[k] += tb[1 + k] * v;
    }
  }
  size_t base = ((size_t)(ho * 33 + hw) * 9) * 258 + 2 * m + ri;
#pragma unroll
  for (int k = 0; k < 9; ++k) psih[base + (size_t)k * 258] = acc[k];
}

__global__ __launch_bounds__(128) void k_psih_int(const int* __restrict__ off,
    const float* __restrict__ tab, const float* __restrict__ tc, const float* __restrict__ ts,
    float* __restrict__ psih)
{
  int ho = blockIdx.x, hi = blockIdx.y;
  int t = threadIdx.x;
  if (t >= 66) return;
  int m = t >> 1, ri = t & 1;
  const float* tw = ri ? ts : tc;
  float acc[9] = {};
  int e0 = off[ho * 33 + hi], e1 = off[ho * 33 + hi + 1];
  const float* tb = tab + ((size_t)ho * ME_INT + e0) * 12;
  for (int e = e0; e < e1; ++e, tb += 12) {
    int d = __float_as_int(tb[0]) & 0xffff;
    float v = tw[(m * d) & 63];
#pragma unroll
    for (int k = 0; k < 9; ++k) acc[k] += tb[1 + k] * v;
  }
  size_t base = ((size_t)(ho * 32 + hi) * 9) * 66 + 2 * m + ri;
#pragma unroll
  for (int k = 0; k < 9; ++k) psih[base + (size_t)k * 66] = acc[k];
}

__global__ __launch_bounds__(320) void k_psih_enc(const int* __restrict__ off,
    const float* __restrict__ tab, const float* __restrict__ tc, const float* __restrict__ ts,
    float* __restrict__ psih)
{
  int ho = blockIdx.x, hw = blockIdx.y;     // (32, 34)
  int hi = 4 * ho - 15 + hw;
  int t = threadIdx.x;
  if (t >= 258) return;
  int m = t >> 1, ri = t & 1;
  const float* tw = ri ? ts : tc;
  float acc[9] = {};
  if (hi >= 0 && hi < 128) {
    int e0 = off[ho * 129 + hi], e1 = off[ho * 129 + hi + 1];
    const float* tb = tab + ((size_t)ho * ME_ENC + e0) * 12;
    for (int e = e0; e < e1; ++e, tb += 12) {
      int d = __float_as_int(tb[0]) & 0xffff;
      float v = tw[(m * d) & 255];
#pragma unroll
      for (int k = 0; k < 9; ++k) acc[k] += tb[1 + k] * v;
    }
  }
  size_t base = ((size_t)(ho * HW_E + hw) * 9) * 258 + 2 * m + ri;
#pragma unroll
  for (int k = 0; k < 9; ++k) psih[base + (size_t)k * 258] = acc[k];
}

// ---------------- m-space encoder conv ----------------
__global__ __launch_bounds__(192) void k_enc_mconv(const float* __restrict__ psih,
    const float* __restrict__ XhE, float* __restrict__ Zh)
{
  int ho = blockIdx.x, cb = blockIdx.y;     // (32, 24)
  int c = cb >> 3, b = cb & 7;
  int m = threadIdx.x;
  if (m > 128) return;
  const float2* X2 = (const float2*)XhE;
  const float2* P2 = (const float2*)psih;
  float zr[9] = {}, zi[9] = {};
  int hi0 = 4 * ho - 15;
  for (int hw = 0; hw < HW_E; ++hw) {
    int hi = hi0 + hw;
    if (hi < 0 || hi > 127) continue;
    float2 xv = X2[((size_t)(b * 3 + c) * 128 + hi) * 129 + m];
    size_t pb = ((size_t)(ho * HW_E + hw) * 9) * 129 + m;
#pragma unroll
    for (int k = 0; k < 9; ++k) {
      float2 p = P2[pb + (size_t)k * 129];
      zr[k] += p.x * xv.x - p.y * xv.y;
      zi[k] += p.x * xv.y + p.y * xv.x;
    }
  }
#pragma unroll
  for (int k = 0; k < 9; ++k)
    ((float2*)Zh)[(((size_t)(c * 9 + k) * 8 + b) * 32 + ho) * 129 + m] =
        make_float2(zr[k], zi[k]);
}

// ---------------- m-space local conv ----------------
__global__ __launch_bounds__(320) void k_int_mconv(const float* __restrict__ xh,
    const float* __restrict__ psih, float* __restrict__ zh, int c0)
{
  int ho = blockIdx.x, g = blockIdx.y, b = blockIdx.z;  // grid (32, 8, 8)
  int t = threadIdx.x;
  if (t >= 264) return;
  int cl = t / 33, m = t % 33;
  int c = c0 + g * 8 + cl;
  const float2* X2 = (const float2*)xh;
  const float2* P2 = (const float2*)psih;
  float zr[9] = {}, zi[9] = {};
  for (int hi = 0; hi < 32; ++hi) {
    float2 xv = X2[((size_t)(c * 8 + b) * 32 + hi) * 33 + m];
    size_t pb = ((size_t)(ho * 32 + hi) * 9) * 33 + m;
#pragma unroll
    for (int k = 0; k < 9; ++k) {
      float2 p = P2[pb + (size_t)k * 33];
      zr[k] += p.x * xv.x - p.y * xv.y;
      zi[k] += p.x * xv.y + p.y * xv.x;
    }
  }
  int crow = (g * 8 + cl) * 9;
#pragma unroll
  for (int k = 0; k < 9; ++k)
    ((float2*)zh)[((size_t)(crow + k)) * 8448 + b * 1056 + ho * 33 + m] =
        make_float2(zr[k], zi[k]);
}

// ---------------- m-space decoder conv (round-7 form: grid (128 ho, 8 b), o folded) ----------------
__global__ __launch_bounds__(192) void k_dec_mconv(const float* __restrict__ psih,
    const float* __restrict__ gh, float* __restrict__ yh)
{
  int ho = blockIdx.x, b = blockIdx.y;
  int m = threadIdx.x;
  if (m > 128) return;
  const float2* P2 = (const float2*)psih;
  const float2* G2 = (const float2*)gh;
  float yr[3] = {}, yi[3] = {};
  for (int hw = 0; hw < 33; ++hw) {
    int hi = ho - 16 + hw;
    if (hi < 0 || hi > 127) continue;
    size_t pb = ((size_t)(ho * 33 + hw) * 9) * 129 + m;
#pragma unroll
    for (int k = 0; k < 9; ++k) {
      float2 p = P2[pb + (size_t)k * 129];
#pragma unroll
      for (int o = 0; o < 3; ++o) {
        float2 gv = G2[((size_t)((o * 9 + k) * 8 + b) * 128 + hi) * 129 + m];
        yr[o] += p.x * gv.x - p.y * gv.y;
        yi[o] += p.x * gv.y + p.y * gv.x;
      }
    }
  }
#pragma unroll
  for (int o = 0; o < 3; ++o)
    ((float2*)yh)[((size_t)(b * 3 + o) * 128 + ho) * 129 + m] = make_float2(yr[o], yi[o]);
}

// ---------------- LDS-tiled SHT analysis ----------------
__global__ __launch_bounds__(64) void k_analysis2(const float* __restrict__ PW,
    const float* __restrict__ XH, u32* __restrict__ c1sp)
{
  int c = blockIdx.x, b = blockIdx.y;
  int t = threadIdx.x;                 // q = 2m+ri, 64
  __shared__ float s[32 * 64];         // [h][q]
  __shared__ float pwl[32 * 33];       // [m][h] padded
  const float* xr = XH + ((size_t)(c * 8 + b) * 32) * 66;
  for (int h = 0; h < 32; ++h) s[h * 64 + t] = xr[h * 66 + t];
  int m = t >> 1;
  for (int l = 0; l < 32; ++l) {
    __syncthreads();
#pragma unroll
    for (int j = 0; j < 16; ++j) {
      int idx = t * 16 + j;
      pwl[(idx >> 5) * 33 + (idx & 31)] = PW[(size_t)l * 1024 + idx];
    }
    __syncthreads();
    float acc = 0.f;
#pragma unroll
    for (int h = 0; h < 32; ++h) acc += pwl[m * 33 + h] * s[h * 64 + t];
    c1sp[(size_t)l * 131072 + c * 512 + b * 64 + t] = packhl(acc);
  }
}

// ---------------- LDS-tiled SHT synthesis ----------------
__global__ __launch_bounds__(64) void k_synth2(const float* __restrict__ PT,
    const float* __restrict__ c2s, float* __restrict__ Xo)
{
  int o = blockIdx.x, b = blockIdx.y;
  int t = threadIdx.x;                 // q
  __shared__ float s2[32 * 64];        // [l][q]
  __shared__ float ptl[32 * 33];       // [m][h] padded
  for (int l = 0; l < 32; ++l)
    s2[l * 64 + t] = c2s[((size_t)(l * 256 + o)) * 512 + b * 64 + t];
  int m = t >> 1;
  float acc[32];
#pragma unroll
  for (int h = 0; h < 32; ++h) acc[h] = 0.f;
  for (int l = 0; l < 32; ++l) {
    __syncthreads();
#pragma unroll
    for (int j = 0; j < 16; ++j) {
      int idx = t * 16 + j;
      ptl[(idx >> 5) * 33 + (idx & 31)] = PT[(size_t)l * 1024 + idx];
    }
    __syncthreads();
    float sv = s2[l * 64 + t];
#pragma unroll
    for (int h = 0; h < 32; ++h) acc[h] += ptl[m * 33 + h] * sv;
  }
  size_t base = ((size_t)(o * 8 + b) * 32) * 64 + t;
#pragma unroll
  for (int h = 0; h < 32; ++h) Xo[base + (size_t)h * 64] = acc[h];
}

// ---------------- MFMA f16x3 split GEMM ----------------
__global__ __launch_bounds__(256) void k_gemm(
    int M, int N, int K,
    const float* __restrict__ A, const u32* __restrict__ Ap, int lda, long long sA,
    const float* __restrict__ Bm, const u32* __restrict__ Bp, int ldb, long long sB,
    float* __restrict__ C, int ldc, long long sC, u32* __restrict__ Cp,
    const float* __restrict__ bias, int flags)
{
  if (A)  A  += (size_t)blockIdx.z * sA;
  if (Ap) Ap += (size_t)blockIdx.z * sA;
  if (Bm) Bm += (size_t)blockIdx.z * sB;
  if (Bp) Bp += (size_t)blockIdx.z * sB;
  if (C)  C  += (size_t)blockIdx.z * sC;
  if (Cp) Cp += (size_t)blockIdx.z * sC;
  __shared__ alignas(16) u16 Ah[128 * 36], Al[128 * 36], Bh[128 * 36], Bl[128 * 36];
  int bm = blockIdx.y * 128, bn = blockIdx.x * 128;
  int tid = threadIdx.x;
  int sr = tid >> 1, k2 = tid & 1;
  int lane = tid & 63, wid = tid >> 6;
  int wr = wid >> 1, wc = wid & 1;
  int lrow = lane & 15, kg = lane >> 4;
  f32x4 acc[4][4] = {};
  bool bok = (bn + sr) < N;

  for (int k0 = 0; k0 < K; k0 += 32) {
    {  // stage A
      u32* ph = (u32*)&Ah[sr * 36 + k2 * 16];
      u32* pl = (u32*)&Al[sr * 36 + k2 * 16];
      if (Ap) {
        const u32* Ar = Ap + (size_t)(bm + sr) * lda + k0 + k2 * 16;
#pragma unroll
        for (int j2 = 0; j2 < 8; ++j2) {
          int gk = k0 + k2 * 16 + 2 * j2;
          u32 w0 = (gk < K)     ? Ar[2 * j2]     : 0u;
          u32 w1 = (gk + 1 < K) ? Ar[2 * j2 + 1] : 0u;
          ph[j2] = (w0 & 0xffffu) | (w1 << 16);
          pl[j2] = (w0 >> 16) | (w1 & 0xffff0000u);
        }
      } else {
        const float* Ar = A + (size_t)(bm + sr) * lda + k0 + k2 * 16;
#pragma unroll
        for (int j2 = 0; j2 < 8; ++j2) {
          int gk = k0 + k2 * 16 + 2 * j2;
          float v0 = (gk < K)     ? Ar[2 * j2]     : 0.f;
          float v1 = (gk + 1 < K) ? Ar[2 * j2 + 1] : 0.f;
          u16 h0 = f16rne(v0), h1 = f16rne(v1);
          u16 l0 = f16rne(v0 - f16tof(h0)), l1 = f16rne(v1 - f16tof(h1));
          ph[j2] = (u32)h0 | ((u32)h1 << 16);
          pl[j2] = (u32)l0 | ((u32)l1 << 16);
        }
      }
    }
    {  // stage B (transpose K-major -> [n][k])
      u32* ph = (u32*)&Bh[sr * 36 + k2 * 16];
      u32* pl = (u32*)&Bl[sr * 36 + k2 * 16];
      if (Bp) {
        const u32* Bc = Bp + bn + sr;
#pragma unroll
        for (int j2 = 0; j2 < 8; ++j2) {
          int gk = k0 + k2 * 16 + 2 * j2;
          u32 w0 = (bok && gk < K)     ? Bc[(size_t)gk * ldb]       : 0u;
          u32 w1 = (bok && gk + 1 < K) ? Bc[(size_t)(gk + 1) * ldb] : 0u;
          ph[j2] = (w0 & 0xffffu) | (w1 << 16);
          pl[j2] = (w0 >> 16) | (w1 & 0xffff0000u);
        }
      } else {
        const float* Bc = Bm + bn + sr;
#pragma unroll
        for (int j2 = 0; j2 < 8; ++j2) {
          int gk = k0 + k2 * 16 + 2 * j2;
          float v0 = (bok && gk < K)     ? Bc[(size_t)gk * ldb]       : 0.f;
          float v1 = (bok && gk + 1 < K) ? Bc[(size_t)(gk + 1) * ldb] : 0.f;
          u16 h0 = f16rne(v0), h1 = f16rne(v1);
          u16 l0 = f16rne(v0 - f16tof(h0)), l1 = f16rne(v1 - f16tof(h1));
          ph[j2] = (u32)h0 | ((u32)h1 << 16);
          pl[j2] = (u32)l0 | ((u32)l1 << 16);
        }
      }
    }
    __syncthreads();
    f16x8 fah[4], fal[4], fbh[4], fbl[4];
#pragma unroll
    for (int i = 0; i < 4; ++i) {
      int ar = wr * 64 + i * 16 + lrow;
      fah[i] = *(const f16x8*)&Ah[ar * 36 + kg * 8];
      fal[i] = *(const f16x8*)&Al[ar * 36 + kg * 8];
      int br = wc * 64 + i * 16 + lrow;
      fbh[i] = *(const f16x8*)&Bh[br * 36 + kg * 8];
      fbl[i] = *(const f16x8*)&Bl[br * 36 + kg * 8];
    }
#pragma unroll
    for (int i = 0; i < 4; ++i)
#pragma unroll
      for (int j = 0; j < 4; ++j) {
        acc[i][j] = __builtin_amdgcn_mfma_f32_16x16x32_f16(fah[i], fbh[j], acc[i][j], 0, 0, 0);
        acc[i][j] = __builtin_amdgcn_mfma_f32_16x16x32_f16(fah[i], fbl[j], acc[i][j], 0, 0, 0);
        acc[i][j] = __builtin_amdgcn_mfma_f32_16x16x32_f16(fal[i], fbh[j], acc[i][j], 0, 0, 0);
      }
    __syncthreads();
  }

#pragma unroll
  for (int i = 0; i < 4; ++i) {
    int gm0 = bm + wr * 64 + i * 16 + kg * 4;
#pragma unroll
    for (int j = 0; j < 4; ++j) {
      int gn = bn + wc * 64 + j * 16 + lrow;
      if (gn >= N) continue;
#pragma unroll
      for (int rr = 0; rr < 4; ++rr) {
        int gm = gm0 + rr;
        size_t idx = (size_t)gm * ldc + gn;
        float v = acc[i][j][rr];
        if (flags & 4) v += bias[gm];
        if (flags & 2) v += C[idx];
        if (flags & 1) v = fmaxf(v, 0.f);
        if (C) C[idx] = v;
        if (flags & 8) Cp[idx] = packhl(v);
      }
    }
  }
}

// small-M GEMM: M=27, K=256, N=16384 (decoder channel mix)
__global__ __launch_bounds__(256) void k_gemm_m27(const float* __restrict__ A,
    const float* __restrict__ Bm, float* __restrict__ C)
{
  int n = blockIdx.x * 256 + threadIdx.x;
  float acc[27] = {};
  for (int k = 0; k < 256; ++k) {
    float bv = Bm[(size_t)k * NSP + n];
#pragma unroll
    for (int m = 0; m < 27; ++m) acc[m] += A[m * 256 + k] * bv;
  }
#pragma unroll
  for (int m = 0; m < 27; ++m) C[(size_t)m * NSP + n] = acc[m];
}

// ---------------- bilinear resample (32,64) -> (128,256), channel-major ----------------
__global__ __launch_bounds__(256) void k_resample(const float* __restrict__ gi, float* __restrict__ gf)
{
  int t = blockIdx.x * 256 + threadIdx.x;
  int WO = t & 255, HO = (t >> 8) & 127, b = (t >> 15) & 7, ok = t >> 18;
  float fi = fminf(fmaxf(HO * 0.25f - 0.375f, 0.f), 31.f);
  int i0 = (int)fi;
  int i1 = min(i0 + 1, 31);
  float wi = fi - (float)i0;
  int j0 = WO >> 2;
  int j1 = (j0 + 1) & 63;
  float wj = (float)(WO & 3) * 0.25f;
  const float* s = gi + (size_t)ok * NSP + b * 2048;
  float v00 = s[i0 * 64 + j0], v01 = s[i0 * 64 + j1];
  float v10 = s[i1 * 64 + j0], v11 = s[i1 * 64 + j1];
  float a0 = v00 * (1.f - wj) + v01 * wj;
  float a1 = v10 * (1.f - wj) + v11 * wj;
  gf[((size_t)ok * 8 + b) * 32768 + HO * 256 + WO] = a0 * (1.f - wi) + a1 * wi;
}

} // namespace

extern "C" void kernel_launch(void* const* d_in, const int* in_sizes, int n_in,
                              void* d_out, int out_size, void* d_ws, size_t ws_size,
                              hipStream_t stream)
{
  const float* x_in  = (const float*)d_in[0];
  const float* enc_w = (const float*)d_in[1];
  const float* lconv = (const float*)d_in[2];
  const float* gconv = (const float*)d_in[3];
  const float* w1    = (const float*)d_in[4];
  const float* b1    = (const float*)d_in[5];
  const float* w2    = (const float*)d_in[6];
  const float* b2    = (const float*)d_in[7];
  const float* skw   = (const float*)d_in[8];
  const float* skb   = (const float*)d_in[9];
  const float* decw  = (const float*)d_in[10];
  float* out = (float*)d_out;

  char* ws = (char*)d_ws;
  size_t off = 0;
  auto alloc = [&](size_t nfloats) -> float* {
    float* p = (float*)(ws + off);
    off += ((nfloats * 4 + 255) / 256) * 256;
    return p;
  };
  float* PW    = alloc(32768);
  float* PT    = alloc(32768);
  float* tc256 = alloc(256);
  float* ts256 = alloc(256);
  float* tc64  = alloc(64);
  float* ts64  = alloc(64);
  u32* TW256p  = (u32*)alloc(256 * 258);
  u32* ITW256p = (u32*)alloc(258 * 256);
  u32* TW64p   = (u32*)alloc(64 * 66);
  u32* ITW64p  = (u32*)alloc(66 * 64);
  u32* IFp     = (u32*)alloc(258 * 64);
  int*   cnt2  = (int*)alloc(21504);
  int*   cnt_enc = cnt2;
  int*   cnt_int = cnt2 + 4096;
  int*   cnt_dec = cnt2 + 5120;
  int*   off_enc = (int*)alloc(32 * 129);
  int*   off_int = (int*)alloc(32 * 33);
  int*   off_dec = (int*)alloc(128 * 129);
  float* decT     = alloc(27 * 256);
  float* psih_dec = alloc((size_t)128 * 33 * 9 * 258);   // 39.2 MB
  float* psih_int = alloc((size_t)32 * 32 * 9 * 66);     // 2.4 MB
  float* psih_enc = alloc((size_t)32 * HW_E * 9 * 258);  // 10.1 MB
  u32* enc_wp = (u32*)alloc(256 * 27);
  u32* w1p    = (u32*)alloc(4 * 512 * 256);
  u32* wsp    = (u32*)alloc(4 * 256 * 768);              // merged [w2|skw] packed
  float* bsum = alloc(4 * 256);
  u32* lconvp = (u32*)alloc(2 * 256 * 2304);
  float* P  = alloc((size_t)EE * NSP);
  float* Q  = alloc((size_t)EE * NSP);
  float* T  = alloc((size_t)EE * NSP);
  u32*   Tp = (u32*)alloc((size_t)EE * NSP);             // packed T (16.8 MB)
  float* U  = alloc(19005440);                           // 76 MB phase-union scratch
  (void)ws_size; (void)in_sizes; (void)n_in; (void)out_size;

  // phase-local aliases inside U (float offsets)
  float* tab_dec = U;                          // setup: 7,077,888
  float* tab_int = U + 7077888;                // setup:   786,432
  float* tab_enc = U + 7864320;                // setup: 1,966,080
  float* zc      = U;                          // encoder:  442,368
  float* XhE     = U + 442368;                 // encoder:  792,576
  float* ZhE     = U + 1234944;                // encoder: 1,783,296
  float* XH      = U;                          // local: 4,325,376
  float* ZH      = U + 4325376;                // local: 9,732,096
  float* XO      = U + 14057472;               // local: 4,325,376
  u32*   gwTlp   = (u32*)U;                    // spectral: 2,097,152 u32
  u32*   c1sp    = (u32*)(U + 2097152);        // spectral: 4,194,304 u32
  float* c2s     = U + 6291456;                // spectral: 4,194,304 f32
  float* Xo_s    = U + 10485760;               // spectral: 4,194,304 f32
  float* XHs     = U + 14680064;               // spectral: 4,325,376 f32
  u32*   Hbp     = (u32*)U;                    // MLP: 8,388,608 u32 (rows 0..511)
  u32*   Pp      = (u32*)(U + 8388608);        // MLP: 4,194,304 u32 (rows 512..767, contiguous!)
  float* g_int   = U;                          // dec:   442,368
  float* g_full  = U + 524288;                 // dec: 7,077,888
  float* GH      = U + 7602176;                // dec: 7,133,184
  float* YH      = U + 14735360;               // dec:   792,576

  const double CUT_LOC = 4.0 * PI_D / 31.0;
  const double CUT_INT = 16.0 * PI_D / 31.0;
  auto splitN = [&](const float* src, u32* dst, int n) {
    int g = (n + 255) / 256; if (g > 2048) g = 2048;
    hipLaunchKernelGGL(k_split, dim3(g), dim3(256), 0, stream, src, dst, n);
  };
  const float* F0 = nullptr; const u32* U0 = nullptr; u32* W0 = nullptr;

  // ---- constants ----
  hipMemsetAsync(cnt2, 0, 21504 * 4, stream);
  hipLaunchKernelGGL(k_legendre, dim3(1), dim3(64), 0, stream, PW, PT);
  hipLaunchKernelGGL(k_tw2, dim3(1), dim3(256), 0, stream, tc256, ts256, tc64, ts64);
  hipLaunchKernelGGL(k_twmat, dim3(129), dim3(256), 0, stream, TW256p, ITW256p, TW64p, ITW64p, IFp);
  hipLaunchKernelGGL(k_decT, dim3(27), dim3(256), 0, stream, decw, decT);
  splitN(enc_w, enc_wp, 256 * 27);
  splitN(w1,    w1p,    4 * 512 * 256);
  hipLaunchKernelGGL(k_mergew, dim3(3072), dim3(256), 0, stream, w2, skw, b2, skb, wsp, bsum);
  splitN(lconv, lconvp, 2 * 256 * 2304);

  hipLaunchKernelGGL(k_psi_count, dim3(128, 32), dim3(256), 0, stream, 128, 256, 32, CUT_LOC, cnt_enc);
  hipLaunchKernelGGL(k_psi_scan,  dim3(32), dim3(1), 0, stream, 128, ME_ENC, cnt_enc, off_enc);
  hipLaunchKernelGGL(k_psi_fill,  dim3(128, 32), dim3(256), 0, stream, 128, 256, 32, CUT_LOC, ME_ENC, cnt_enc, off_enc, tab_enc);

  hipLaunchKernelGGL(k_psi_count, dim3(32, 32), dim3(64), 0, stream, 32, 64, 32, CUT_INT, cnt_int);
  hipLaunchKernelGGL(k_psi_scan,  dim3(32), dim3(1), 0, stream, 32, ME_INT, cnt_int, off_int);
  hipLaunchKernelGGL(k_psi_fill,  dim3(32, 32), dim3(64), 0, stream, 32, 64, 32, CUT_INT, ME_INT, cnt_int, off_int, tab_int);

  hipLaunchKernelGGL(k_psi_count, dim3(128, 128), dim3(256), 0, stream, 128, 256, 128, CUT_LOC, cnt_dec);
  hipLaunchKernelGGL(k_psi_scan,  dim3(128), dim3(1), 0, stream, 128, ME_DEC, cnt_dec, off_dec);
  hipLaunchKernelGGL(k_psi_fill,  dim3(128, 128), dim3(256), 0, stream, 128, 256, 128, CUT_LOC, ME_DEC, cnt_dec, off_dec, tab_dec);

  hipLaunchKernelGGL(k_psih_dec, dim3(128, 33), dim3(320), 0, stream, off_dec, tab_dec, tc256, ts256, psih_dec);
  hipLaunchKernelGGL(k_psih_int, dim3(32, 32),  dim3(128), 0, stream, off_int, tab_int, tc64, ts64, psih_int);
  hipLaunchKernelGGL(k_psih_enc, dim3(32, HW_E), dim3(320), 0, stream, off_enc, tab_enc, tc256, ts256, psih_enc);

  // ---- encoder in m-space: rfft256(x) -> mconv -> folded irfft (stride 4) -> channel mix ----
  hipLaunchKernelGGL(k_gemm, dim3(3, 24, 1), dim3(256), 0, stream,
                     3072, 258, 256, x_in, U0, 256, 0LL, F0, TW256p, 258, 0LL,
                     XhE, 258, 0LL, W0, F0, 0);
  hipLaunchKernelGGL(k_enc_mconv, dim3(32, 24), dim3(192), 0, stream, psih_enc, XhE, ZhE);
  hipLaunchKernelGGL(k_gemm, dim3(1, 54, 1), dim3(256), 0, stream,
                     6912, 64, 258, ZhE, U0, 258, 0LL, F0, IFp, 64, 0LL,
                     zc, 64, 0LL, W0, F0, 0);
  hipLaunchKernelGGL(k_gemm, dim3(128, 2, 1), dim3(256), 0, stream,
                     256, NSP, 27, F0, enc_wp, 27, 0LL, zc, U0, NSP, 0LL,
                     P, NSP, 0LL, W0, F0, 0);

  // ---- 4 blocks ----
  for (int i = 0; i < 4; ++i) {
    int layer = i >> 1;
    if ((i & 1) == 0) {
      // local DISCO block in m-space
      hipLaunchKernelGGL(k_gemm, dim3(1, 512, 1), dim3(256), 0, stream,
                         65536, 66, 64, P, U0, 64, 0LL, F0, TW64p, 66, 0LL,
                         XH, 66, 0LL, W0, F0, 0);
      for (int cc = 0; cc < 4; ++cc) {
        hipLaunchKernelGGL(k_int_mconv, dim3(32, 8, 8), dim3(320), 0, stream,
                           XH, psih_int, ZH, cc * 64);
        hipLaunchKernelGGL(k_gemm, dim3(132, 2, 1), dim3(256), 0, stream,
                           256, 16896, 576,
                           F0, lconvp + (size_t)layer * 589824 + cc * 576, 2304, 0LL,
                           ZH, U0, 16896, 0LL,
                           XO, 16896, 0LL, W0, F0, cc ? 2 : 0);
      }
      hipLaunchKernelGGL(k_gemm, dim3(1, 512, 1), dim3(256), 0, stream,
                         65536, 64, 66, XO, U0, 66, 0LL, F0, ITW64p, 64, 0LL,
                         T, 64, 0LL, Tp, F0, 8);
    } else {
      // spectral (SHT) block: rfft GEMM -> analysis2 -> gconv GEMM -> synth2 -> irfft GEMM
      hipLaunchKernelGGL(k_gwT_lp, dim3(8192), dim3(256), 0, stream,
                         gconv + (size_t)layer * 2097152, gwTlp);
      hipLaunchKernelGGL(k_gemm, dim3(1, 512, 1), dim3(256), 0, stream,
                         65536, 66, 64, P, U0, 64, 0LL, F0, TW64p, 66, 0LL,
                         XHs, 66, 0LL, W0, F0, 0);
      hipLaunchKernelGGL(k_analysis2, dim3(256, 8), dim3(64), 0, stream, PW, XHs, c1sp);
      hipLaunchKernelGGL(k_gemm, dim3(4, 2, 32), dim3(256), 0, stream,
                         256, 512, 256,
                         F0, gwTlp, 256, 65536LL, F0, c1sp, 512, 131072LL,
                         c2s, 512, 131072LL, W0, F0, 0);
      hipLaunchKernelGGL(k_synth2, dim3(256, 8), dim3(64), 0, stream, PT, c2s, Xo_s);
      hipLaunchKernelGGL(k_gemm, dim3(1, 512, 1), dim3(256), 0, stream,
                         65536, 64, 64, Xo_s, U0, 64, 0LL, F0, ITW64p, 64, 0LL,
                         T, 64, 0LL, Tp, F0, 8);
    }
    // MLP + linear skip as ONE merged GEMM:  Q = [w2|skw]·[relu(w1·T+b1); P] + (b2+skb)
    hipLaunchKernelGGL(k_gemm, dim3(128, 4, 1), dim3(256), 0, stream,
                       512, NSP, 256, F0, w1p + (size_t)i * 131072, 256, 0LL,
                       F0, Tp, NSP, 0LL,
                       (float*)nullptr, NSP, 0LL, Hbp, b1 + (size_t)i * 512, 1 | 4 | 8);
    splitN(P, Pp, EE * NSP);
    hipLaunchKernelGGL(k_gemm, dim3(128, 2, 1), dim3(256), 0, stream,
                       256, NSP, 768, F0, wsp + (size_t)i * 196608, 768, 0LL,
                       F0, Hbp, NSP, 0LL,
                       Q, NSP, 0LL, W0, bsum + (size_t)i * 256, 4);
    std::swap(P, Q);
  }

  // ---- decoder: mix E->27, resample, m-space conv (DFTs as GEMMs) ----
  hipLaunchKernelGGL(k_gemm_m27, dim3(64), dim3(256), 0, stream, decT, P, g_int);
  hipLaunchKernelGGL(k_resample, dim3(27648), dim3(256), 0, stream, g_int, g_full);
  hipLaunchKernelGGL(k_gemm, dim3(3, 216, 1), dim3(256), 0, stream,
                     27648, 258, 256, g_full, U0, 256, 0LL, F0, TW256p, 258, 0LL,
                     GH, 258, 0LL, W0, F0, 0);
  hipLaunchKernelGGL(k_dec_mconv, dim3(128, 8), dim3(192), 0, stream, psih_dec, GH, YH);
  hipLaunchKernelGGL(k_gemm, dim3(2, 24, 1), dim3(256), 0, stream,
                     3072, 256, 258, YH, U0, 258, 0LL, F0, ITW256p, 256, 0LL,
                     out, 256, 0LL, W0, F0, 0);
}